// Round 1
// baseline (690.632 us; speedup 1.0000x reference)
//
#include <hip/hip_runtime.h>
#include <math.h>

#define T_TOKENS 8192
#define HID 7168
#define NEXP 256
#define TOPK 8
#define NGRP 8
#define TOPKG 4
#define RSCALE 2.5f

#define BM 32
#define BK 32
#define ASTRIDE 36   // padded [BK][36] so b128 reads stay 16B-aligned, writes spread banks

__global__ __launch_bounds__(256) void gemm_logits_f32(
    const float* __restrict__ A,    // [T_TOKENS][HID]
    const float* __restrict__ W,    // [NEXP][HID]
    float* __restrict__ out)        // [T_TOKENS][NEXP]
{
    __shared__ float As[2][BK][ASTRIDE];
    __shared__ float Bs[2][BK][NEXP];

    const int tid = threadIdx.x;
    const int m0 = blockIdx.x * BM;

    // staging: A tile 32x32: thread -> (row = tid/8, 4 k's at (tid%8)*4)
    const int arow = tid >> 3;
    const int akq  = (tid & 7) << 2;
    // B tile 256x32: thread = expert, loads 32 k's (8 float4)

    // compute: thread tile 4(M) x 8(N); N split as [4*tn .. +3] and [128+4*tn .. +3]
    const int tm = tid >> 5;   // 0..7
    const int tn = tid & 31;   // 0..31

    const float* Aptr = A + (size_t)(m0 + arow) * HID + akq;
    const float* Wptr = W + (size_t)tid * HID;

    float4 aReg;
    float4 bReg[8];

    float acc[4][8];
#pragma unroll
    for (int i = 0; i < 4; ++i)
#pragma unroll
        for (int j = 0; j < 8; ++j) acc[i][j] = 0.f;

    // prefetch tile 0
    aReg = *(const float4*)(Aptr);
#pragma unroll
    for (int q = 0; q < 8; ++q) bReg[q] = *(const float4*)(Wptr + 4 * q);

    // write buffer 0
#pragma unroll
    for (int j = 0; j < 4; ++j) As[0][akq + j][arow] = ((const float*)&aReg)[j];
#pragma unroll
    for (int q = 0; q < 8; ++q)
#pragma unroll
        for (int j = 0; j < 4; ++j) Bs[0][4 * q + j][tid] = ((const float*)&bReg[q])[j];
    __syncthreads();

    const int NT = HID / BK;   // 224
    for (int t = 0; t < NT; ++t) {
        const int cur = t & 1;
        if (t + 1 < NT) {
            const float* ap = Aptr + (size_t)(t + 1) * BK;
            aReg = *(const float4*)ap;
            const float* wp = Wptr + (size_t)(t + 1) * BK;
#pragma unroll
            for (int q = 0; q < 8; ++q) bReg[q] = *(const float4*)(wp + 4 * q);
        }
#pragma unroll
        for (int k = 0; k < BK; ++k) {
            float4 a  = *(const float4*)&As[cur][k][4 * tm];
            float4 b0 = *(const float4*)&Bs[cur][k][4 * tn];
            float4 b1 = *(const float4*)&Bs[cur][k][128 + 4 * tn];
            const float av[4] = {a.x, a.y, a.z, a.w};
            const float bv[8] = {b0.x, b0.y, b0.z, b0.w, b1.x, b1.y, b1.z, b1.w};
#pragma unroll
            for (int i = 0; i < 4; ++i)
#pragma unroll
                for (int j = 0; j < 8; ++j)
                    acc[i][j] = fmaf(av[i], bv[j], acc[i][j]);
        }
        if (t + 1 < NT) {
            __syncthreads();
            const int nxt = cur ^ 1;
#pragma unroll
            for (int j = 0; j < 4; ++j) As[nxt][akq + j][arow] = ((const float*)&aReg)[j];
#pragma unroll
            for (int q = 0; q < 8; ++q)
#pragma unroll
                for (int j = 0; j < 4; ++j) Bs[nxt][4 * q + j][tid] = ((const float*)&bReg[q])[j];
            __syncthreads();
        }
    }

#pragma unroll
    for (int i = 0; i < 4; ++i) {
        size_t row = (size_t)(m0 + 4 * tm + i);
        float4 r0 = {acc[i][0], acc[i][1], acc[i][2], acc[i][3]};
        float4 r1 = {acc[i][4], acc[i][5], acc[i][6], acc[i][7]};
        *(float4*)&out[row * NEXP + 4 * tn] = r0;
        *(float4*)&out[row * NEXP + 128 + 4 * tn] = r1;
    }
}

// One wave per token. Lane l owns experts 4l..4l+3 (all within group l>>3).
__global__ __launch_bounds__(64) void route_topk(
    const float* __restrict__ logits,
    const float* __restrict__ bias,
    float* __restrict__ outw,
    float* __restrict__ outi)
{
    const int t = blockIdx.x;
    const int l = threadIdx.x;

    float4 lg  = *(const float4*)&logits[(size_t)t * NEXP + 4 * l];
    float4 bv4 = *(const float4*)&bias[4 * l];

    const float lgv[4] = {lg.x, lg.y, lg.z, lg.w};
    const float bb[4]  = {bv4.x, bv4.y, bv4.z, bv4.w};
    float s[4], c[4];
#pragma unroll
    for (int j = 0; j < 4; ++j) {
        s[j] = 1.0f / (1.0f + expf(-lgv[j]));
        c[j] = s[j] + bb[j];
    }

    // local top-2 of the 4 corrected scores (values only; sum is tie-insensitive)
    float m1 = fmaxf(c[0], c[1]), n1 = fminf(c[0], c[1]);
    float m2 = fmaxf(c[2], c[3]), n2 = fminf(c[2], c[3]);
    float v1 = fmaxf(m1, m2);
    float v2 = fmaxf(fminf(m1, m2), (m1 >= m2) ? n1 : n2);

    // merge sorted top-2 pairs across the 8 lanes of each group
#pragma unroll
    for (int off = 1; off < 8; off <<= 1) {
        float o1 = __shfl_xor(v1, off, 64);
        float o2 = __shfl_xor(v2, off, 64);
        float nv1 = fmaxf(v1, o1);
        float nv2 = fmaxf(fminf(v1, o1), (v1 >= o1) ? v2 : o2);
        v1 = nv1; v2 = nv2;
    }
    const float gsum = v1 + v2;   // my group's score (uniform within octet)

    const int myg = l >> 3;
    int rank = 0;
#pragma unroll
    for (int g = 0; g < 8; ++g) {
        float gv = __shfl(gsum, g * 8, 64);
        rank += (gv > gsum) || ((gv == gsum) && (g < myg));
    }
    const bool sel = rank < TOPKG;

    // masked scores exactly per reference: unselected groups -> 0.0 (NOT -inf)
    float mv[4];
#pragma unroll
    for (int j = 0; j < 4; ++j) mv[j] = sel ? c[j] : 0.0f;

    float wsel[8];
    int   isel[8];
#pragma unroll
    for (int r = 0; r < TOPK; ++r) {
        // lane-local argmax, lowest index on tie
        float bvv = mv[0]; int bi = (l << 2);
#pragma unroll
        for (int j = 1; j < 4; ++j) {
            if (mv[j] > bvv) { bvv = mv[j]; bi = (l << 2) + j; }
        }
        // wave-wide argmax, lowest index on tie
#pragma unroll
        for (int off = 32; off >= 1; off >>= 1) {
            float ov = __shfl_xor(bvv, off, 64);
            int   oi = __shfl_xor(bi,  off, 64);
            if (ov > bvv || (ov == bvv && oi < bi)) { bvv = ov; bi = oi; }
        }
        const int owner = bi >> 2, slot = bi & 3;
        float myv = 0.f;
#pragma unroll
        for (int j = 0; j < 4; ++j) if (j == slot) myv = s[j];   // sigmoid, no bias
        float sv = __shfl(myv, owner, 64);
        wsel[r] = sv; isel[r] = bi;
        if (l == owner) {
#pragma unroll
            for (int j = 0; j < 4; ++j) if (j == slot) mv[j] = -1e30f;
        }
    }

    float denom = 0.f;
#pragma unroll
    for (int r = 0; r < TOPK; ++r) denom += wsel[r];
    denom += 1e-20f;

    if (l == 0) {
#pragma unroll
        for (int r = 0; r < TOPK; ++r) {
            float wn = wsel[r] / denom;
            outw[(size_t)t * TOPK + r] = wn * RSCALE;
            outi[(size_t)t * TOPK + r] = (float)isel[r];
        }
    }
}

extern "C" void kernel_launch(void* const* d_in, const int* in_sizes, int n_in,
                              void* d_out, int out_size, void* d_ws, size_t ws_size,
                              hipStream_t stream)
{
    const float* hs   = (const float*)d_in[0];
    const float* w    = (const float*)d_in[1];
    const float* bias = (const float*)d_in[2];

    float* logits = (float*)d_out;
    float* outw   = logits + (size_t)T_TOKENS * NEXP;
    float* outi   = outw   + (size_t)T_TOKENS * TOPK;

    gemm_logits_f32<<<T_TOKENS / BM, 256, 0, stream>>>(hs, w, logits);
    route_topk<<<T_TOKENS, 64, 0, stream>>>(logits, bias, outw, outi);
}

// Round 2
// 456.644 us; speedup vs baseline: 1.5124x; 1.5124x over previous
//
#include <hip/hip_runtime.h>
#include <math.h>

#define T_TOKENS 8192
#define HID 7168
#define NEXP 256
#define TOPK 8
#define TOPKG 4
#define RSCALE 2.5f

#define BM 32
#define BK 16
#define AS_STRIDE 36   // padded; k-row base 144B stays 16B-aligned, writes spread banks

// C[t][e] partials: out[ks][token][expert], K-slice ks covers HID/NSPLIT columns.
template<int NSPLIT>
__global__ __launch_bounds__(256, 4) void gemm_logits_f32(
    const float* __restrict__ A,    // [T_TOKENS][HID]
    const float* __restrict__ W,    // [NEXP][HID]
    float* __restrict__ out)        // [NSPLIT][T_TOKENS][NEXP]
{
    __shared__ float As[2][BK][AS_STRIDE];
    __shared__ float Bs[2][BK][NEXP];

    const int tid = threadIdx.x;
    const int mt  = blockIdx.x & 255;        // token tile
    const int ks  = blockIdx.x >> 8;         // k slice
    const int m0  = mt * BM;
    const int KS  = HID / NSPLIT;            // k's per slice
    const int kbase = ks * KS;
    const int NT  = KS / BK;

    // staging: A tile 32 rows x 16 k: thread -> (row = tid/8, 2 k's at (tid%8)*2)
    const int arow = tid >> 3;
    const int akq  = (tid & 7) << 1;
    // B tile 256 experts x 16 k: thread = expert tid, 4 float4

    // compute: thread tile 4(M) x 8(N); N split [4*tn..+3] and [128+4*tn..+3]
    const int tm = tid >> 5;   // 0..7
    const int tn = tid & 31;   // 0..31

    const float* Aptr = A + (size_t)(m0 + arow) * HID + kbase + akq;
    const float* Wptr = W + (size_t)tid * HID + kbase;

    float2 aReg;
    float4 bReg[4];

    float acc[4][8];
#pragma unroll
    for (int i = 0; i < 4; ++i)
#pragma unroll
        for (int j = 0; j < 8; ++j) acc[i][j] = 0.f;

    // prefetch tile 0
    aReg = *(const float2*)(Aptr);
#pragma unroll
    for (int q = 0; q < 4; ++q) bReg[q] = *(const float4*)(Wptr + 4 * q);

    // write buffer 0
    As[0][akq + 0][arow] = aReg.x;
    As[0][akq + 1][arow] = aReg.y;
#pragma unroll
    for (int q = 0; q < 4; ++q)
#pragma unroll
        for (int j = 0; j < 4; ++j) Bs[0][4 * q + j][tid] = ((const float*)&bReg[q])[j];
    __syncthreads();

    for (int t = 0; t < NT; ++t) {
        const int cur = t & 1;
        if (t + 1 < NT) {
            const float* ap = Aptr + (size_t)(t + 1) * BK;
            aReg = *(const float2*)ap;
            const float* wp = Wptr + (size_t)(t + 1) * BK;
#pragma unroll
            for (int q = 0; q < 4; ++q) bReg[q] = *(const float4*)(wp + 4 * q);
        }
#pragma unroll
        for (int k = 0; k < BK; ++k) {
            float4 a  = *(const float4*)&As[cur][k][4 * tm];
            float4 b0 = *(const float4*)&Bs[cur][k][4 * tn];
            float4 b1 = *(const float4*)&Bs[cur][k][128 + 4 * tn];
            const float av[4] = {a.x, a.y, a.z, a.w};
            const float bv[8] = {b0.x, b0.y, b0.z, b0.w, b1.x, b1.y, b1.z, b1.w};
#pragma unroll
            for (int i = 0; i < 4; ++i)
#pragma unroll
                for (int j = 0; j < 8; ++j)
                    acc[i][j] = fmaf(av[i], bv[j], acc[i][j]);
        }
        if (t + 1 < NT) {
            __syncthreads();
            const int nxt = cur ^ 1;
            As[nxt][akq + 0][arow] = aReg.x;
            As[nxt][akq + 1][arow] = aReg.y;
#pragma unroll
            for (int q = 0; q < 4; ++q)
#pragma unroll
                for (int j = 0; j < 4; ++j) Bs[nxt][4 * q + j][tid] = ((const float*)&bReg[q])[j];
            __syncthreads();
        }
    }

    float* obase = out + (size_t)ks * T_TOKENS * NEXP;
#pragma unroll
    for (int i = 0; i < 4; ++i) {
        size_t row = (size_t)(m0 + 4 * tm + i);
        float4 r0 = {acc[i][0], acc[i][1], acc[i][2], acc[i][3]};
        float4 r1 = {acc[i][4], acc[i][5], acc[i][6], acc[i][7]};
        *(float4*)&obase[row * NEXP + 4 * tn] = r0;
        *(float4*)&obase[row * NEXP + 128 + 4 * tn] = r1;
    }
}

// 4 tokens per 256-thread block; wave w -> token 4*bid+w. Lane l owns experts 4l..4l+3.
// Sums NSPLIT partial slices from src, writes final logits, then exact top-k routing.
template<int NSPLIT>
__global__ __launch_bounds__(256) void route_topk(
    const float* __restrict__ src,      // [NSPLIT][T][E] partials
    const float* __restrict__ bias,
    float* __restrict__ logits,         // [T][E] final
    float* __restrict__ outw,
    float* __restrict__ outi)
{
    const int t = blockIdx.x * 4 + (threadIdx.x >> 6);
    const int l = threadIdx.x & 63;

    float4 lg = {0.f, 0.f, 0.f, 0.f};
#pragma unroll
    for (int s = 0; s < NSPLIT; ++s) {
        float4 p = *(const float4*)&src[((size_t)s * T_TOKENS + t) * NEXP + 4 * l];
        lg.x += p.x; lg.y += p.y; lg.z += p.z; lg.w += p.w;
    }
    *(float4*)&logits[(size_t)t * NEXP + 4 * l] = lg;

    float4 bv4 = *(const float4*)&bias[4 * l];

    const float lgv[4] = {lg.x, lg.y, lg.z, lg.w};
    const float bb[4]  = {bv4.x, bv4.y, bv4.z, bv4.w};
    float s[4], c[4];
#pragma unroll
    for (int j = 0; j < 4; ++j) {
        s[j] = 1.0f / (1.0f + expf(-lgv[j]));
        c[j] = s[j] + bb[j];
    }

    // local top-2 of the 4 corrected scores
    float m1 = fmaxf(c[0], c[1]), n1 = fminf(c[0], c[1]);
    float m2 = fmaxf(c[2], c[3]), n2 = fminf(c[2], c[3]);
    float v1 = fmaxf(m1, m2);
    float v2 = fmaxf(fminf(m1, m2), (m1 >= m2) ? n1 : n2);

    // merge sorted top-2 pairs across the 8 lanes of each group
#pragma unroll
    for (int off = 1; off < 8; off <<= 1) {
        float o1 = __shfl_xor(v1, off, 64);
        float o2 = __shfl_xor(v2, off, 64);
        float nv1 = fmaxf(v1, o1);
        float nv2 = fmaxf(fminf(v1, o1), (v1 >= o1) ? v2 : o2);
        v1 = nv1; v2 = nv2;
    }
    const float gsum = v1 + v2;   // group score, uniform within octet

    const int myg = l >> 3;
    int rank = 0;
#pragma unroll
    for (int g = 0; g < 8; ++g) {
        float gv = __shfl(gsum, g * 8, 64);
        rank += (gv > gsum) || ((gv == gsum) && (g < myg));
    }
    const bool sel = rank < TOPKG;

    // masked scores: unselected groups -> 0.0 exactly per reference
    float mv[4];
#pragma unroll
    for (int j = 0; j < 4; ++j) mv[j] = sel ? c[j] : 0.0f;

    float wsel[8];
    int   isel[8];
#pragma unroll
    for (int r = 0; r < TOPK; ++r) {
        float bvv = mv[0]; int bi = (l << 2);
#pragma unroll
        for (int j = 1; j < 4; ++j) {
            if (mv[j] > bvv) { bvv = mv[j]; bi = (l << 2) + j; }
        }
#pragma unroll
        for (int off = 32; off >= 1; off >>= 1) {
            float ov = __shfl_xor(bvv, off, 64);
            int   oi = __shfl_xor(bi,  off, 64);
            if (ov > bvv || (ov == bvv && oi < bi)) { bvv = ov; bi = oi; }
        }
        const int owner = bi >> 2, slot = bi & 3;
        float myv = 0.f;
#pragma unroll
        for (int j = 0; j < 4; ++j) if (j == slot) myv = s[j];   // raw sigmoid
        float sv = __shfl(myv, owner, 64);
        wsel[r] = sv; isel[r] = bi;
        if (l == owner) {
#pragma unroll
            for (int j = 0; j < 4; ++j) if (j == slot) mv[j] = -1e30f;
        }
    }

    float denom = 0.f;
#pragma unroll
    for (int r = 0; r < TOPK; ++r) denom += wsel[r];
    denom += 1e-20f;

    if (l == 0) {
#pragma unroll
        for (int r = 0; r < TOPK; ++r) {
            float wn = wsel[r] / denom;
            outw[(size_t)t * TOPK + r] = wn * RSCALE;
            outi[(size_t)t * TOPK + r] = (float)isel[r];
        }
    }
}

extern "C" void kernel_launch(void* const* d_in, const int* in_sizes, int n_in,
                              void* d_out, int out_size, void* d_ws, size_t ws_size,
                              hipStream_t stream)
{
    const float* hs   = (const float*)d_in[0];
    const float* w    = (const float*)d_in[1];
    const float* bias = (const float*)d_in[2];

    float* logits = (float*)d_out;
    float* outw   = logits + (size_t)T_TOKENS * NEXP;
    float* outi   = outw   + (size_t)T_TOKENS * TOPK;

    const size_t need4 = (size_t)4 * T_TOKENS * NEXP * sizeof(float);
    if (ws_size >= need4) {
        float* part = (float*)d_ws;
        gemm_logits_f32<4><<<4 * (T_TOKENS / BM), 256, 0, stream>>>(hs, w, part);
        route_topk<4><<<T_TOKENS / 4, 256, 0, stream>>>(part, bias, logits, outw, outi);
    } else {
        gemm_logits_f32<1><<<T_TOKENS / BM, 256, 0, stream>>>(hs, w, logits);
        route_topk<1><<<T_TOKENS / 4, 256, 0, stream>>>(logits, bias, logits, outw, outi);
    }
}

// Round 4
// 177.869 us; speedup vs baseline: 3.8828x; 2.5673x over previous
//
#include <hip/hip_runtime.h>
#include <math.h>

#define T_TOKENS 8192
#define HID 7168
#define NEXP 256
#define TOPK 8
#define TOPKG 4
#define RSCALE 2.5f
#define BM 64
#define KT 32

#define F16_MIN_NORMAL 6.103515625e-05f
#define LO_SCALE 4096.0f
#define LO_INV   (1.0f / 4096.0f)

typedef _Float16 f16;
typedef f16 f16x8 __attribute__((ext_vector_type(8)));
typedef f16 f16x4 __attribute__((ext_vector_type(4)));
typedef float f32x4 __attribute__((ext_vector_type(4)));

// swizzled f16 index within a [rows][64]-f16 plane (8 chunks of 16B per 128B row)
__device__ __forceinline__ int sidx(int row, int c) {
    return row * 64 + ((c ^ (row & 7)) << 3);
}

// split x into f16 hi (flushed to 0 if subnormal) + f16 lo = (x - hi)*4096
__device__ __forceinline__ void split_f16(float x, f16& h, f16& l) {
    h = (f16)x;
    float hf = (float)h;
    if (fabsf(hf) < F16_MIN_NORMAL) { h = (f16)0.0f; hf = 0.0f; }
    l = (f16)((x - hf) * LO_SCALE);
}

// W fp32 -> f16 hi/lo planes (lo pre-scaled by 4096)
__global__ __launch_bounds__(256) void convert_w(
    const float* __restrict__ W, f16* __restrict__ Wh, f16* __restrict__ Wl)
{
    const size_t i = ((size_t)blockIdx.x * 256 + threadIdx.x) * 8;
    float4 x0 = *(const float4*)&W[i];
    float4 x1 = *(const float4*)&W[i + 4];
    const float xs[8] = {x0.x, x0.y, x0.z, x0.w, x1.x, x1.y, x1.z, x1.w};
    f16x8 h, l;
#pragma unroll
    for (int j = 0; j < 8; ++j) {
        f16 hh, ll;
        split_f16(xs[j], hh, ll);
        h[j] = hh; l[j] = ll;
    }
    *(f16x8*)&Wh[i] = h;
    *(f16x8*)&Wl[i] = l;
}

// C[t][e] = sum_k A[t][k] * W[e][k] via 3-term f16 split MFMA with scaled residuals:
//   C = acc_hh + (acc_{ah*bl'} + acc_{al'*bh}) / 4096,  where lo' = lo*4096.
template<int NS>
__global__ __launch_bounds__(512, 4) void gemm_f16x3(
    const float* __restrict__ A,
    const f16* __restrict__ Wh, const f16* __restrict__ Wl,
    float* __restrict__ out0,      // slice 0 partial (= logits region)
    float* __restrict__ partw)     // slices 1..NS-1
{
    constexpr int KSLICE = HID / NS;
    constexpr int NCHUNK = KSLICE / KT;

    __shared__ f16 lA[2][BM * 64];     //  [64 rows][32 hi | 32 lo]
    __shared__ f16 lB[2][NEXP * 64];   //  [256 experts][32 hi | 32 lo]

    const int tid = threadIdx.x;

    // chunked XCD swizzle (grid % 8 == 0 -> bijective)
    const int nb = 128 * NS;
    const int chunkB = nb >> 3;
    const int logical = (blockIdx.x & 7) * chunkB + (blockIdx.x >> 3);
    const int ks = logical / 128;
    const int mt = logical % 128;
    const int m0 = mt * BM;
    const int kbase = ks * KSLICE;

    // staging roles
    const int ar  = tid >> 3;            // A row 0..63
    const int akq = (tid & 7) << 2;      // A k offset {0,4,..,28}
    const int br  = tid >> 1;            // B expert row 0..255
    const int bkq = (tid & 1) << 4;      // B k offset {0,16}

    const float* Ag = A  + (size_t)(m0 + ar) * HID + kbase + akq;
    const f16*  Whg = Wh + (size_t)br * HID + kbase + bkq;
    const f16*  Wlg = Wl + (size_t)br * HID + kbase + bkq;

    // wave geometry: 8 waves 2(M) x 4(N); wave tile 32 x 64
    const int w  = tid >> 6;
    const int l  = tid & 63;
    const int wm = w >> 2;          // 0..1
    const int wn = w & 3;           // 0..3
    const int fr = l & 15;
    const int fk = l >> 4;          // k-chunk 0..3 (hi), +4 for lo

    f32x4 acc [2][4];   // hh terms
    f32x4 accm[2][4];   // scaled cross terms
#pragma unroll
    for (int i = 0; i < 2; ++i)
#pragma unroll
        for (int j = 0; j < 4; ++j) {
            acc [i][j] = (f32x4){0.f, 0.f, 0.f, 0.f};
            accm[i][j] = (f32x4){0.f, 0.f, 0.f, 0.f};
        }

    float4 aReg;
    f16x8 wh0, wh1, wl0, wl1;

    auto stage = [&](int buf) {
        f16x4 h, lo;
        const float xs[4] = {aReg.x, aReg.y, aReg.z, aReg.w};
#pragma unroll
        for (int j = 0; j < 4; ++j) {
            f16 hh, ll;
            split_f16(xs[j], hh, ll);
            h[j] = hh; lo[j] = ll;
        }
        f16* LA = &lA[buf][0];
        *(f16x4*)&LA[sidx(ar, (akq >> 3)) + (akq & 7)]     = h;
        *(f16x4*)&LA[sidx(ar, 4 + (akq >> 3)) + (akq & 7)] = lo;
        f16* LB = &lB[buf][0];
        const int c0 = bkq >> 3;
        *(f16x8*)&LB[sidx(br, c0)]         = wh0;
        *(f16x8*)&LB[sidx(br, c0 + 1)]     = wh1;
        *(f16x8*)&LB[sidx(br, 4 + c0)]     = wl0;
        *(f16x8*)&LB[sidx(br, 4 + c0 + 1)] = wl1;
    };

    // prologue: chunk 0
    aReg = *(const float4*)Ag;
    wh0 = *(const f16x8*)Whg;       wh1 = *(const f16x8*)(Whg + 8);
    wl0 = *(const f16x8*)Wlg;       wl1 = *(const f16x8*)(Wlg + 8);
    stage(0);
    __syncthreads();

    for (int t = 0; t < NCHUNK; ++t) {
        const int cur = t & 1;
        const bool more = (t + 1) < NCHUNK;
        if (more) {
            const int ko = (t + 1) * KT;
            aReg = *(const float4*)(Ag + ko);
            wh0 = *(const f16x8*)(Whg + ko); wh1 = *(const f16x8*)(Whg + ko + 8);
            wl0 = *(const f16x8*)(Wlg + ko); wl1 = *(const f16x8*)(Wlg + ko + 8);
        }

        const f16* LA = &lA[cur][0];
        const f16* LB = &lB[cur][0];

        f16x8 ah[2], al[2];
#pragma unroll
        for (int mi = 0; mi < 2; ++mi) {
            const int row = wm * 32 + mi * 16 + fr;
            ah[mi] = *(const f16x8*)&LA[sidx(row, fk)];
            al[mi] = *(const f16x8*)&LA[sidx(row, 4 + fk)];
        }
#pragma unroll
        for (int ni = 0; ni < 4; ++ni) {
            const int row = wn * 64 + ni * 16 + fr;
            f16x8 bh = *(const f16x8*)&LB[sidx(row, fk)];
            f16x8 bl = *(const f16x8*)&LB[sidx(row, 4 + fk)];
#pragma unroll
            for (int mi = 0; mi < 2; ++mi) {
                acc [mi][ni] = __builtin_amdgcn_mfma_f32_16x16x32_f16(ah[mi], bh, acc [mi][ni], 0, 0, 0);
                accm[mi][ni] = __builtin_amdgcn_mfma_f32_16x16x32_f16(ah[mi], bl, accm[mi][ni], 0, 0, 0);
                accm[mi][ni] = __builtin_amdgcn_mfma_f32_16x16x32_f16(al[mi], bh, accm[mi][ni], 0, 0, 0);
            }
        }

        if (more) stage(cur ^ 1);
        __syncthreads();
    }

    float* obase = (ks == 0) ? out0 : (partw + (size_t)(ks - 1) * T_TOKENS * NEXP);
#pragma unroll
    for (int mi = 0; mi < 2; ++mi) {
#pragma unroll
        for (int ni = 0; ni < 4; ++ni) {
            const int row0 = m0 + wm * 32 + mi * 16 + fk * 4;
            const int col  = wn * 64 + ni * 16 + fr;
#pragma unroll
            for (int r = 0; r < 4; ++r)
                obase[(size_t)(row0 + r) * NEXP + col] =
                    acc[mi][ni][r] + accm[mi][ni][r] * LO_INV;
        }
    }
}

// 4 tokens per 256-thread block. Sums NS partial slices (slice 0 in logits
// region), writes final logits in place, then exact top-k routing.
template<int NS>
__global__ __launch_bounds__(256) void route_topk(
    const float* __restrict__ part0,
    const float* __restrict__ partw,
    const float* __restrict__ bias,
    float* __restrict__ logits,
    float* __restrict__ outw,
    float* __restrict__ outi)
{
    const int t = blockIdx.x * 4 + (threadIdx.x >> 6);
    const int l = threadIdx.x & 63;

    float4 lg = *(const float4*)&part0[(size_t)t * NEXP + 4 * l];
#pragma unroll
    for (int s = 0; s + 1 < NS; ++s) {
        float4 p = *(const float4*)&partw[((size_t)s * T_TOKENS + t) * NEXP + 4 * l];
        lg.x += p.x; lg.y += p.y; lg.z += p.z; lg.w += p.w;
    }
    *(float4*)&logits[(size_t)t * NEXP + 4 * l] = lg;

    float4 bv4 = *(const float4*)&bias[4 * l];
    const float lgv[4] = {lg.x, lg.y, lg.z, lg.w};
    const float bb[4]  = {bv4.x, bv4.y, bv4.z, bv4.w};
    float s[4], c[4];
#pragma unroll
    for (int j = 0; j < 4; ++j) {
        s[j] = 1.0f / (1.0f + expf(-lgv[j]));
        c[j] = s[j] + bb[j];
    }

    // group top-2 sum
    float m1 = fmaxf(c[0], c[1]), n1 = fminf(c[0], c[1]);
    float m2 = fmaxf(c[2], c[3]), n2 = fminf(c[2], c[3]);
    float v1 = fmaxf(m1, m2);
    float v2 = fmaxf(fminf(m1, m2), (m1 >= m2) ? n1 : n2);
#pragma unroll
    for (int off = 1; off < 8; off <<= 1) {
        float o1 = __shfl_xor(v1, off, 64);
        float o2 = __shfl_xor(v2, off, 64);
        float nv1 = fmaxf(v1, o1);
        float nv2 = fmaxf(fminf(v1, o1), (v1 >= o1) ? v2 : o2);
        v1 = nv1; v2 = nv2;
    }
    const float gsum = v1 + v2;

    const int myg = l >> 3;
    int rank = 0;
#pragma unroll
    for (int g = 0; g < 8; ++g) {
        float gv = __shfl(gsum, g * 8, 64);
        rank += (gv > gsum) || ((gv == gsum) && (g < myg));
    }
    const bool sel = rank < TOPKG;

    float mv[4];
#pragma unroll
    for (int j = 0; j < 4; ++j) mv[j] = sel ? c[j] : 0.0f;

    float wsel[8];
    int   isel[8];
#pragma unroll
    for (int r = 0; r < TOPK; ++r) {
        float bvv = mv[0]; int bi = (l << 2);
#pragma unroll
        for (int j = 1; j < 4; ++j) {
            if (mv[j] > bvv) { bvv = mv[j]; bi = (l << 2) + j; }
        }
#pragma unroll
        for (int off = 32; off >= 1; off >>= 1) {
            float ov = __shfl_xor(bvv, off, 64);
            int   oi = __shfl_xor(bi,  off, 64);
            if (ov > bvv || (ov == bvv && oi < bi)) { bvv = ov; bi = oi; }
        }
        const int owner = bi >> 2, slot = bi & 3;
        float myv = 0.f;
#pragma unroll
        for (int j = 0; j < 4; ++j) if (j == slot) myv = s[j];
        float sv = __shfl(myv, owner, 64);
        wsel[r] = sv; isel[r] = bi;
        if (l == owner) {
#pragma unroll
            for (int j = 0; j < 4; ++j) if (j == slot) mv[j] = -1e30f;
        }
    }

    float denom = 0.f;
#pragma unroll
    for (int r = 0; r < TOPK; ++r) denom += wsel[r];
    denom += 1e-20f;

    if (l == 0) {
#pragma unroll
        for (int r = 0; r < TOPK; ++r) {
            float wn = wsel[r] / denom;
            outw[(size_t)t * TOPK + r] = wn * RSCALE;
            outi[(size_t)t * TOPK + r] = (float)isel[r];
        }
    }
}

extern "C" void kernel_launch(void* const* d_in, const int* in_sizes, int n_in,
                              void* d_out, int out_size, void* d_ws, size_t ws_size,
                              hipStream_t stream)
{
    const float* hs   = (const float*)d_in[0];
    const float* w    = (const float*)d_in[1];
    const float* bias = (const float*)d_in[2];

    float* logits = (float*)d_out;
    float* outw   = logits + (size_t)T_TOKENS * NEXP;
    float* outi   = outw   + (size_t)T_TOKENS * TOPK;

    const size_t partBytes = (size_t)3 * T_TOKENS * NEXP * sizeof(float);  // 25.17 MB
    const size_t wBytes    = (size_t)NEXP * HID * sizeof(f16);             // 3.67 MB

    if (ws_size >= partBytes + 2 * wBytes) {
        float* partw = (float*)d_ws;
        f16* Wh = (f16*)((char*)d_ws + partBytes);
        f16* Wl = Wh + (size_t)NEXP * HID;
        convert_w<<<NEXP * HID / 2048, 256, 0, stream>>>(w, Wh, Wl);
        gemm_f16x3<4><<<128 * 4, 512, 0, stream>>>(hs, Wh, Wl, logits, partw);
        route_topk<4><<<T_TOKENS / 4, 256, 0, stream>>>(logits, partw, bias, logits, outw, outi);
    } else {
        f16* Wh = (f16*)d_ws;
        f16* Wl = Wh + (size_t)NEXP * HID;
        convert_w<<<NEXP * HID / 2048, 256, 0, stream>>>(w, Wh, Wl);
        gemm_f16x3<1><<<128, 512, 0, stream>>>(hs, Wh, Wl, logits, logits);
        route_topk<1><<<T_TOKENS / 4, 256, 0, stream>>>(logits, logits, bias, logits, outw, outi);
    }
}

// Round 5
// 141.625 us; speedup vs baseline: 4.8765x; 1.2559x over previous
//
#include <hip/hip_runtime.h>
#include <math.h>

#define T_TOKENS 8192
#define HID 7168
#define NEXP 256
#define TOPK 8
#define TOPKG 4
#define RSCALE 2.5f
#define BM 128
#define KT 32
#define NCHUNK_ALL (HID / KT)          // 224 k-chunks total
#define PANEL_F16 (NEXP * 64)          // f16 elements per chunk panel (32 KB)

#define F16_MIN_NORMAL 6.103515625e-05f
#define LO_SCALE 4096.0f
#define LO_INV   (1.0f / 4096.0f)

typedef _Float16 f16;
typedef f16 f16x8 __attribute__((ext_vector_type(8)));
typedef float f32x4 __attribute__((ext_vector_type(4)));

// swizzled f16 index within a [rows][64]-f16 plane; c in [0,8) (c<4 hi, c>=4 lo)
__device__ __forceinline__ int sidx(int row, int c) {
    return row * 64 + ((c ^ (row & 7)) << 3);
}

__device__ __forceinline__ void split_f16(float x, f16& h, f16& l) {
    h = (f16)x;
    float hf = (float)h;
    if (fabsf(hf) < F16_MIN_NORMAL) { h = (f16)0.0f; hf = 0.0f; }
    l = (f16)((x - hf) * LO_SCALE);
}

__device__ __forceinline__ void gload16(const void* g, void* l) {
    __builtin_amdgcn_global_load_lds(
        (const __attribute__((address_space(1))) unsigned int*)g,
        (__attribute__((address_space(3))) unsigned int*)l, 16, 0, 0);
}

// W fp32 -> swizzled f16 hi/lo chunk panels: Wp[t][row][swz-pos], t = k-chunk.
// Panel row layout == GEMM LDS image, so staging is a linear 32 KB copy.
__global__ __launch_bounds__(256) void convert_w(
    const float* __restrict__ W, f16* __restrict__ Wp)
{
    const int idx = blockIdx.x * 256 + threadIdx.x;   // 224*256*4 threads
    const int c = idx & 3;
    const int r = (idx >> 2) & 255;
    const int t = idx >> 10;

    const float* src = W + (size_t)r * HID + t * KT + c * 8;
    float4 x0 = *(const float4*)src;
    float4 x1 = *(const float4*)(src + 4);
    const float xs[8] = {x0.x, x0.y, x0.z, x0.w, x1.x, x1.y, x1.z, x1.w};
    f16x8 h, l;
#pragma unroll
    for (int j = 0; j < 8; ++j) {
        f16 hh, ll;
        split_f16(xs[j], hh, ll);
        h[j] = hh; l[j] = ll;
    }
    f16* prow = Wp + (size_t)t * PANEL_F16 + r * 64;
    *(f16x8*)&prow[(( c      ^ (r & 7)) << 3)] = h;
    *(f16x8*)&prow[(((4 + c) ^ (r & 7)) << 3)] = l;
}

// C[t][e] = sum_k A[t][k]*W[e][k] via 3-term f16 split MFMA (scaled residuals).
template<int NS>
__global__ __launch_bounds__(512, 2) void gemm_f16x3(
    const float* __restrict__ A,
    const f16* __restrict__ Wp,
    float* __restrict__ out0,      // slice 0 partial (= logits region)
    float* __restrict__ partw)     // slices 1..NS-1
{
    constexpr int NCH = (HID / NS) / KT;   // chunks per slice
    constexpr int MB  = T_TOKENS / BM;     // 64 m-tiles

    __shared__ f16 lA[2][BM * 64];         // 16 KB per buffer
    __shared__ f16 lB[2][NEXP * 64];       // 32 KB per buffer

    const int tid = threadIdx.x;

    // chunked XCD swizzle (grid = MB*NS, divisible by 8 -> bijective)
    const int nb = MB * NS;
    const int chunkB = nb >> 3;
    const int logical = (blockIdx.x & 7) * chunkB + (blockIdx.x >> 3);
    const int ks = logical / MB;
    const int mt = logical % MB;
    const int m0 = mt * BM;

    // A staging: thread -> row tid>>2 (0..127), chunk-quarter c = tid&3 (8 k's)
    const int arow = tid >> 2;
    const int ac   = tid & 3;
    const float* Ag = A + (size_t)(m0 + arow) * HID + ks * (HID / NS) + ac * 8;

    // wave geometry: 8 waves 2(M) x 4(N); wave tile 64 x 64
    const int w  = tid >> 6;
    const int l  = tid & 63;
    const int wm = w >> 2;
    const int wn = w & 3;
    const int fr = l & 15;
    const int fk = l >> 4;

    f32x4 acc [4][4];
    f32x4 accm[4][4];
#pragma unroll
    for (int i = 0; i < 4; ++i)
#pragma unroll
        for (int j = 0; j < 4; ++j) {
            acc [i][j] = (f32x4){0.f, 0.f, 0.f, 0.f};
            accm[i][j] = (f32x4){0.f, 0.f, 0.f, 0.f};
        }

    float4 aR0, aR1;

    auto issueB = [&](int buf, int tg) {
        const f16* pan = Wp + (size_t)tg * PANEL_F16;
        const int seg = (w * 4) << 9;                 // wave segment, f16 units (4 KB)
#pragma unroll
        for (int i = 0; i < 4; ++i) {
            const int off = seg + (i << 9) + (l << 3);  // per-lane 16 B
            gload16(pan + off, &lB[buf][seg + (i << 9)]);
        }
    };
    auto writeA = [&](int buf) {
        const float xs[8] = {aR0.x, aR0.y, aR0.z, aR0.w, aR1.x, aR1.y, aR1.z, aR1.w};
        f16x8 h, lo;
#pragma unroll
        for (int j = 0; j < 8; ++j) {
            f16 hh, ll;
            split_f16(xs[j], hh, ll);
            h[j] = hh; lo[j] = ll;
        }
        f16* LA = &lA[buf][0];
        *(f16x8*)&LA[sidx(arow, ac)]     = h;
        *(f16x8*)&LA[sidx(arow, 4 + ac)] = lo;
    };

    // prologue: chunk 0
    aR0 = *(const float4*)Ag;
    aR1 = *(const float4*)(Ag + 4);
    issueB(0, ks * NCH);
    writeA(0);
    __syncthreads();

    for (int t = 0; t < NCH; ++t) {
        const int cur = t & 1;
        const bool more = (t + 1) < NCH;
        if (more) {
            const float* ap = Ag + (size_t)(t + 1) * KT;
            aR0 = *(const float4*)ap;
            aR1 = *(const float4*)(ap + 4);
            issueB(cur ^ 1, ks * NCH + t + 1);
        }

        const f16* LA = &lA[cur][0];
        const f16* LB = &lB[cur][0];

        f16x8 ah[4], al[4];
#pragma unroll
        for (int mi = 0; mi < 4; ++mi) {
            const int row = wm * 64 + mi * 16 + fr;
            ah[mi] = *(const f16x8*)&LA[sidx(row, fk)];
            al[mi] = *(const f16x8*)&LA[sidx(row, 4 + fk)];
        }
        __builtin_amdgcn_s_setprio(1);
#pragma unroll
        for (int ni = 0; ni < 4; ++ni) {
            const int row = wn * 64 + ni * 16 + fr;
            f16x8 bh = *(const f16x8*)&LB[sidx(row, fk)];
            f16x8 bl = *(const f16x8*)&LB[sidx(row, 4 + fk)];
#pragma unroll
            for (int mi = 0; mi < 4; ++mi) {
                acc [mi][ni] = __builtin_amdgcn_mfma_f32_16x16x32_f16(ah[mi], bh, acc [mi][ni], 0, 0, 0);
                accm[mi][ni] = __builtin_amdgcn_mfma_f32_16x16x32_f16(ah[mi], bl, accm[mi][ni], 0, 0, 0);
                accm[mi][ni] = __builtin_amdgcn_mfma_f32_16x16x32_f16(al[mi], bh, accm[mi][ni], 0, 0, 0);
            }
        }
        __builtin_amdgcn_s_setprio(0);

        if (more) writeA(cur ^ 1);
        __syncthreads();
    }

    float* obase = (ks == 0) ? out0 : (partw + (size_t)(ks - 1) * T_TOKENS * NEXP);
#pragma unroll
    for (int mi = 0; mi < 4; ++mi) {
#pragma unroll
        for (int ni = 0; ni < 4; ++ni) {
            const int row0 = m0 + wm * 64 + mi * 16 + fk * 4;
            const int col  = wn * 64 + ni * 16 + fr;
#pragma unroll
            for (int r = 0; r < 4; ++r)
                obase[(size_t)(row0 + r) * NEXP + col] =
                    acc[mi][ni][r] + accm[mi][ni][r] * LO_INV;
        }
    }
}

// 4 tokens per 256-thread block; exact reference top-k routing.
template<int NS>
__global__ __launch_bounds__(256) void route_topk(
    const float* __restrict__ part0,
    const float* __restrict__ partw,
    const float* __restrict__ bias,
    float* __restrict__ logits,
    float* __restrict__ outw,
    float* __restrict__ outi)
{
    const int t = blockIdx.x * 4 + (threadIdx.x >> 6);
    const int l = threadIdx.x & 63;

    float4 lg = *(const float4*)&part0[(size_t)t * NEXP + 4 * l];
#pragma unroll
    for (int s = 0; s + 1 < NS; ++s) {
        float4 p = *(const float4*)&partw[((size_t)s * T_TOKENS + t) * NEXP + 4 * l];
        lg.x += p.x; lg.y += p.y; lg.z += p.z; lg.w += p.w;
    }
    *(float4*)&logits[(size_t)t * NEXP + 4 * l] = lg;

    float4 bv4 = *(const float4*)&bias[4 * l];
    const float lgv[4] = {lg.x, lg.y, lg.z, lg.w};
    const float bb[4]  = {bv4.x, bv4.y, bv4.z, bv4.w};
    float s[4], c[4];
#pragma unroll
    for (int j = 0; j < 4; ++j) {
        s[j] = 1.0f / (1.0f + expf(-lgv[j]));
        c[j] = s[j] + bb[j];
    }

    float m1 = fmaxf(c[0], c[1]), n1 = fminf(c[0], c[1]);
    float m2 = fmaxf(c[2], c[3]), n2 = fminf(c[2], c[3]);
    float v1 = fmaxf(m1, m2);
    float v2 = fmaxf(fminf(m1, m2), (m1 >= m2) ? n1 : n2);
#pragma unroll
    for (int off = 1; off < 8; off <<= 1) {
        float o1 = __shfl_xor(v1, off, 64);
        float o2 = __shfl_xor(v2, off, 64);
        float nv1 = fmaxf(v1, o1);
        float nv2 = fmaxf(fminf(v1, o1), (v1 >= o1) ? v2 : o2);
        v1 = nv1; v2 = nv2;
    }
    const float gsum = v1 + v2;

    const int myg = l >> 3;
    int rank = 0;
#pragma unroll
    for (int g = 0; g < 8; ++g) {
        float gv = __shfl(gsum, g * 8, 64);
        rank += (gv > gsum) || ((gv == gsum) && (g < myg));
    }
    const bool sel = rank < TOPKG;

    float mv[4];
#pragma unroll
    for (int j = 0; j < 4; ++j) mv[j] = sel ? c[j] : 0.0f;

    float wsel[8];
    int   isel[8];
#pragma unroll
    for (int r = 0; r < TOPK; ++r) {
        float bvv = mv[0]; int bi = (l << 2);
#pragma unroll
        for (int j = 1; j < 4; ++j) {
            if (mv[j] > bvv) { bvv = mv[j]; bi = (l << 2) + j; }
        }
#pragma unroll
        for (int off = 32; off >= 1; off >>= 1) {
            float ov = __shfl_xor(bvv, off, 64);
            int   oi = __shfl_xor(bi,  off, 64);
            if (ov > bvv || (ov == bvv && oi < bi)) { bvv = ov; bi = oi; }
        }
        const int owner = bi >> 2, slot = bi & 3;
        float myv = 0.f;
#pragma unroll
        for (int j = 0; j < 4; ++j) if (j == slot) myv = s[j];
        float sv = __shfl(myv, owner, 64);
        wsel[r] = sv; isel[r] = bi;
        if (l == owner) {
#pragma unroll
            for (int j = 0; j < 4; ++j) if (j == slot) mv[j] = -1e30f;
        }
    }

    float denom = 0.f;
#pragma unroll
    for (int r = 0; r < TOPK; ++r) denom += wsel[r];
    denom += 1e-20f;

    if (l == 0) {
#pragma unroll
        for (int r = 0; r < TOPK; ++r) {
            float wn = wsel[r] / denom;
            outw[(size_t)t * TOPK + r] = wn * RSCALE;
            outi[(size_t)t * TOPK + r] = (float)isel[r];
        }
    }
}

extern "C" void kernel_launch(void* const* d_in, const int* in_sizes, int n_in,
                              void* d_out, int out_size, void* d_ws, size_t ws_size,
                              hipStream_t stream)
{
    const float* hs   = (const float*)d_in[0];
    const float* w    = (const float*)d_in[1];
    const float* bias = (const float*)d_in[2];

    float* logits = (float*)d_out;
    float* outw   = logits + (size_t)T_TOKENS * NEXP;
    float* outi   = outw   + (size_t)T_TOKENS * TOPK;

    const size_t partBytes  = (size_t)3 * T_TOKENS * NEXP * sizeof(float);      // 25.17 MB
    const size_t panelBytes = (size_t)NCHUNK_ALL * PANEL_F16 * sizeof(f16);     // 7.34 MB

    if (ws_size >= partBytes + panelBytes) {
        float* partw = (float*)d_ws;
        f16* Wp = (f16*)((char*)d_ws + partBytes);
        convert_w<<<NCHUNK_ALL * 4, 256, 0, stream>>>(w, Wp);
        gemm_f16x3<4><<<(T_TOKENS / BM) * 4, 512, 0, stream>>>(hs, Wp, logits, partw);
        route_topk<4><<<T_TOKENS / 4, 256, 0, stream>>>(logits, partw, bias, logits, outw, outi);
    } else {
        f16* Wp = (f16*)d_ws;
        convert_w<<<NCHUNK_ALL * 4, 256, 0, stream>>>(w, Wp);
        gemm_f16x3<1><<<T_TOKENS / BM, 512, 0, stream>>>(hs, Wp, logits, logits);
        route_topk<1><<<T_TOKENS / 4, 256, 0, stream>>>(logits, logits, bias, logits, outw, outi);
    }
}